// Round 16
// baseline (450.458 us; speedup 1.0000x reference)
//
#include <hip/hip_runtime.h>
#include <cstddef>
#include <cstdint>

// GraphSAGE (3x SAGEConv mean-aggr + FC) on MI355X.
// Round 15 = R14 (best, 439.1us) + two low-risk changes:
//  - 4-way neighbor-split gathers (R10's 2-way win doubled): TPN=4*CH,
//    quarters combined with shfl_xor(CH) + shfl_xor(2CH). Same VGPR,
//    2x independent load streams -> better latency hiding.
//  - csr_count fused with prep_split (independent work, one launch):
//    blocks [0,EB) histogram edges, rest split x/W. Saves serialization.
// Kept: R14's GEMM1/2 (2-term, 24KB LDS), R10's exact GEMM3+FC kernel,
// bucketed-shuffle CSR, dual layout, hi-only activations, split-bf16 weights.

typedef unsigned int uint_t;
typedef unsigned short ushort_t;
typedef __attribute__((ext_vector_type(8))) short short8;
typedef __attribute__((ext_vector_type(4))) float f32x4;

#define N_IN 64
#define N_HID 128
#define N_OUT 9
#define EB 512          // edge blocks for P1/P3
#define NBUCK_MAX 800   // >= ceil(M/128)
#define YT_STRIDE 134   // y-tile LDS stride (ushorts) for FC epilogue

__device__ __forceinline__ ushort_t f2bf(float f) {   // fp32 -> bf16 RNE
    uint_t u = __float_as_uint(f);
    u += 0x7fffu + ((u >> 16) & 1u);
    return (ushort_t)(u >> 16);
}
__device__ __forceinline__ float bf2f(ushort_t h) {
    return __uint_as_float(((uint_t)h) << 16);
}
__device__ __forceinline__ void async_ld16(const void* g, void* l) {
    __builtin_amdgcn_global_load_lds((const __attribute__((address_space(1))) void*)g,
                                     (__attribute__((address_space(3))) void*)l, 16, 0, 0);
}

// ------- fused: csr_count (blocks 0..EB-1) + prep_split (rest) -------------
__global__ __launch_bounds__(256) void csr_count_prep(
    const int* __restrict__ dst, uint_t* __restrict__ cnt,
    int E, int nbuck, int chunk,
    const float* __restrict__ X, ushort_t* __restrict__ xh,
    ushort_t* __restrict__ xrow, int M,
    const float* __restrict__ Wl1, const float* __restrict__ Wr1,
    const float* __restrict__ Wl2, const float* __restrict__ Wr2,
    const float* __restrict__ Wl3, const float* __restrict__ Wr3,
    ushort_t* __restrict__ w1lh, ushort_t* __restrict__ w1ll,
    ushort_t* __restrict__ w1rh, ushort_t* __restrict__ w1rl,
    ushort_t* __restrict__ w2lh, ushort_t* __restrict__ w2ll,
    ushort_t* __restrict__ w2rh, ushort_t* __restrict__ w2rl,
    ushort_t* __restrict__ w3lh, ushort_t* __restrict__ w3ll,
    ushort_t* __restrict__ w3rh, ushort_t* __restrict__ w3rl)
{
    if (blockIdx.x < EB) {
        __shared__ uint_t c[NBUCK_MAX];
        for (int i = threadIdx.x; i < nbuck; i += 256) c[i] = 0;
        __syncthreads();
        const int beg = blockIdx.x * chunk;
        const int end = min(beg + chunk, E);
        for (int i = beg + threadIdx.x; i < end; i += 256)
            atomicAdd(&c[dst[i] >> 7], 1u);           // LDS atomic
        __syncthreads();
        for (int i = threadIdx.x; i < nbuck; i += 256)
            cnt[(size_t)blockIdx.x * nbuck + i] = c[i];
        return;
    }
    int idx = (blockIdx.x - EB) * 256 + threadIdx.x;
    const int xn = M * 8;
    if (idx < xn) {
        const int node = idx >> 3;
        const int ch = idx & 7;
        const float4 f0 = *(const float4*)(X + (size_t)node * 64 + ch * 8);
        const float4 f1 = *(const float4*)(X + (size_t)node * 64 + ch * 8 + 4);
        float e[8] = {f0.x, f0.y, f0.z, f0.w, f1.x, f1.y, f1.z, f1.w};
        uint_t hv[4];
#pragma unroll
        for (int t = 0; t < 4; ++t) {
            ushort_t h0 = f2bf(e[2 * t]), h1 = f2bf(e[2 * t + 1]);
            hv[t] = (uint_t)h0 | ((uint_t)h1 << 16);
        }
        const size_t off = ((size_t)(node >> 7) * 8 + ch) * 1024 + (node & 127) * 8;
        const uint4 hq = make_uint4(hv[0], hv[1], hv[2], hv[3]);
        *(uint4*)(xh + off) = hq;
        *(uint4*)(xrow + (size_t)node * 64 + ch * 8) = hq;
        return;
    }
    idx -= xn;
    const float* W; ushort_t* th; ushort_t* tl; int K, N, e;
    if (idx < 8192)        { W = Wl1; th = w1lh; tl = w1ll; K = 64;  N = 128; e = idx; }
    else if (idx < 16384)  { W = Wr1; th = w1rh; tl = w1rl; K = 64;  N = 128; e = idx - 8192; }
    else if (idx < 32768)  { W = Wl2; th = w2lh; tl = w2ll; K = 128; N = 128; e = idx - 16384; }
    else if (idx < 49152)  { W = Wr2; th = w2rh; tl = w2rl; K = 128; N = 128; e = idx - 32768; }
    else if (idx < 81920)  { W = Wl3; th = w3lh; tl = w3ll; K = 128; N = 256; e = idx - 49152; }
    else if (idx < 114688) { W = Wr3; th = w3rh; tl = w3rl; K = 128; N = 256; e = idx - 81920; }
    else return;
    int k = e / N, n = e - k * N;
    float v = W[e];
    ushort_t hb = f2bf(v);
    const size_t off = ((size_t)(n >> 7) * (K >> 3) + (k >> 3)) * 1024 + (n & 127) * 8 + (k & 7);
    th[off] = hb;
    tl[off] = f2bf(v - bf2f(hb));
}

__global__ __launch_bounds__(512) void csr_colscan(uint_t* __restrict__ cnt,
                                                   uint_t* __restrict__ total, int nbuck) {
    __shared__ uint_t sm[512];
    const int b = blockIdx.x;
    const uint_t v = cnt[(size_t)threadIdx.x * nbuck + b];
    sm[threadIdx.x] = v;
    __syncthreads();
    for (int off = 1; off < 512; off <<= 1) {
        uint_t t = (threadIdx.x >= off) ? sm[threadIdx.x - off] : 0;
        __syncthreads();
        sm[threadIdx.x] += t;
        __syncthreads();
    }
    cnt[(size_t)threadIdx.x * nbuck + b] = sm[threadIdx.x] - v;   // exclusive
    if (threadIdx.x == 511) total[b] = sm[511];
}

__global__ __launch_bounds__(1024) void top_scan_1024(const uint_t* __restrict__ total,
                                                      uint_t* __restrict__ basev, int nb) {
    __shared__ uint_t sm[1024];
    const int i = threadIdx.x;
    const uint_t v = (i < nb) ? total[i] : 0;
    sm[i] = v;
    __syncthreads();
    for (int off = 1; off < 1024; off <<= 1) {
        uint_t t = (i >= off) ? sm[i - off] : 0;
        __syncthreads();
        sm[i] += t;
        __syncthreads();
    }
    if (i < nb) basev[i] = sm[i] - v;   // exclusive
}

__global__ __launch_bounds__(256) void csr_scatter(const int* __restrict__ src,
                                                   const int* __restrict__ dst,
                                                   const uint_t* __restrict__ cnt,
                                                   const uint_t* __restrict__ basev,
                                                   uint_t* __restrict__ ebuf,
                                                   int E, int nbuck, int chunk) {
    __shared__ uint_t cur[NBUCK_MAX];
    for (int i = threadIdx.x; i < nbuck; i += 256)
        cur[i] = basev[i] + cnt[(size_t)blockIdx.x * nbuck + i];
    __syncthreads();
    const int beg = blockIdx.x * chunk;
    const int end = min(beg + chunk, E);
    for (int i = beg + threadIdx.x; i < end; i += 256) {
        const int d = dst[i];
        const uint_t pos = atomicAdd(&cur[d >> 7], 1u);   // LDS atomic
        ebuf[pos] = ((uint_t)src[i] << 7) | (uint_t)(d & 127);
    }
}

__global__ __launch_bounds__(256) void csr_final(const uint_t* __restrict__ ebuf,
                                                 const uint_t* __restrict__ basev,
                                                 const uint_t* __restrict__ total,
                                                 int* __restrict__ colA,
                                                 int* __restrict__ row_start,
                                                 int* __restrict__ degi,
                                                 float* __restrict__ invdeg, int M) {
    __shared__ uint_t c128[128];
    __shared__ uint_t cur[128];
    __shared__ uint_t sm[256];
    const int b = blockIdx.x;
    const int nbase = b << 7;
    const uint_t e0 = basev[b];
    const uint_t T = total[b];
    if (threadIdx.x < 128) c128[threadIdx.x] = 0;
    __syncthreads();
    for (uint_t i = threadIdx.x; i < T; i += 256)
        atomicAdd(&c128[ebuf[e0 + i] & 127], 1u);
    __syncthreads();
    const uint_t v = (threadIdx.x < 128) ? c128[threadIdx.x] : 0;
    sm[threadIdx.x] = v;
    __syncthreads();
    for (int off = 1; off < 128; off <<= 1) {
        uint_t t = (threadIdx.x >= off) ? sm[threadIdx.x - off] : 0;
        __syncthreads();
        sm[threadIdx.x] += t;
        __syncthreads();
    }
    if (threadIdx.x < 128) {
        const uint_t ex = sm[threadIdx.x] - v;   // exclusive within bucket
        cur[threadIdx.x] = ex;
        const int node = nbase + threadIdx.x;
        if (node < M) {
            degi[node] = (int)v;
            invdeg[node] = 1.0f / fmaxf((float)v, 1.0f);
            row_start[node] = (int)(e0 + ex);
        }
    }
    __syncthreads();
    for (uint_t i = threadIdx.x; i < T; i += 256) {
        const uint_t p = ebuf[e0 + i];
        const uint_t pos = atomicAdd(&cur[p & 127], 1u);
        colA[e0 + pos] = (int)(p >> 7);
    }
}

// ---------------- gather-mean (ROW-MAJOR hi input, tiled HI output) ----------
// 4-way neighbor-split: 4*CH threads/node, quarter q sums [cnt*q/4, cnt*(q+1)/4);
// combined with shfl_xor(CH) + shfl_xor(2CH); quarter 0 stores.
__device__ __forceinline__ void acc8_hi(float* a, uint4 h) {
    a[0] += __uint_as_float(h.x << 16);
    a[1] += __uint_as_float(h.x & 0xffff0000u);
    a[2] += __uint_as_float(h.y << 16);
    a[3] += __uint_as_float(h.y & 0xffff0000u);
    a[4] += __uint_as_float(h.z << 16);
    a[5] += __uint_as_float(h.z & 0xffff0000u);
    a[6] += __uint_as_float(h.w << 16);
    a[7] += __uint_as_float(h.w & 0xffff0000u);
}

template <int CH>
__global__ __launch_bounds__(256) void gather_mean_hi(
    const ushort_t* __restrict__ fh, const int* __restrict__ colA,
    const int* __restrict__ row_start, const int* __restrict__ degi,
    const float* __restrict__ invdeg,
    ushort_t* __restrict__ oh, int M)
{
    constexpr int TPN = 4 * CH;           // threads per node
    constexpr int SLOTS = 256 / TPN;
    constexpr int DIM = CH * 8;
    const int tid = threadIdx.x;
    const int ch = tid & (CH - 1);
    const int q = (tid / CH) & 3;
    const int slot = tid / TPN;
    const int node = blockIdx.x * SLOTS + slot;
    if (node >= M) return;
    const int beg = row_start[node];
    const int cnt = degi[node];
    const int jb = (cnt * q) >> 2;
    const int je = (cnt * (q + 1)) >> 2;
    float a[8];
#pragma unroll
    for (int t = 0; t < 8; ++t) a[t] = 0.f;
    int j = jb;
    for (; j + 3 < je; j += 4) {
        const int s0 = colA[beg + j];
        const int s1 = colA[beg + j + 1];
        const int s2 = colA[beg + j + 2];
        const int s3 = colA[beg + j + 3];
        const uint4 h0 = *(const uint4*)(fh + (size_t)s0 * DIM + ch * 8);
        const uint4 h1 = *(const uint4*)(fh + (size_t)s1 * DIM + ch * 8);
        const uint4 h2 = *(const uint4*)(fh + (size_t)s2 * DIM + ch * 8);
        const uint4 h3 = *(const uint4*)(fh + (size_t)s3 * DIM + ch * 8);
        acc8_hi(a, h0);
        acc8_hi(a, h1);
        acc8_hi(a, h2);
        acc8_hi(a, h3);
    }
    for (; j < je; ++j) {
        const int s0 = colA[beg + j];
        const uint4 h0 = *(const uint4*)(fh + (size_t)s0 * DIM + ch * 8);
        acc8_hi(a, h0);
    }
    // combine quarters (partners within same wave for CH=8/16)
#pragma unroll
    for (int t = 0; t < 8; ++t) a[t] += __shfl_xor(a[t], CH);
#pragma unroll
    for (int t = 0; t < 8; ++t) a[t] += __shfl_xor(a[t], 2 * CH);
    if (tid & (3 * CH)) return;           // only quarter 0 stores
    const float sc = invdeg[node];
    uint_t hv[4];
#pragma unroll
    for (int t = 0; t < 4; ++t) {
        ushort_t hb0 = f2bf(a[2 * t] * sc), hb1 = f2bf(a[2 * t + 1] * sc);
        hv[t] = (uint_t)hb0 | ((uint_t)hb1 << 16);
    }
    const size_t off = ((size_t)(node >> 7) * CH + ch) * 1024 + (node & 127) * 8;
    *(uint4*)(oh + off) = make_uint4(hv[0], hv[1], hv[2], hv[3]);
}

// ---------------- 2-term GEMM (layers 1-2): 24KB LDS ------------------------
__global__ __launch_bounds__(256) void mfma_sage_gemm2(
    const ushort_t* __restrict__ Amh, const ushort_t* __restrict__ Axh,
    const ushort_t* __restrict__ Blh, const ushort_t* __restrict__ Bll,
    const ushort_t* __restrict__ Brh, const ushort_t* __restrict__ Brl,
    const float* __restrict__ bias, ushort_t* __restrict__ Oh,
    ushort_t* __restrict__ Orow,
    int M, int K, int N)
{
    __shared__ ushort_t As_h[4096];
    __shared__ ushort_t Bs_h[4096];
    __shared__ ushort_t Bs_l[4096];

    const int tid  = threadIdx.x;
    const int lane = tid & 63;
    const int wave = tid >> 6;
    const int wm = (wave & 1) * 64;
    const int wn = (wave >> 1) * 64;
    const int l15 = lane & 15;
    const int quad = lane >> 4;
    const int bm = blockIdx.x * 128;
    const int bn = blockIdx.y * 128;
    const int KC = K >> 3;

    const int s0 = wave * 1024 + lane * 8;
    const int s1 = s0 + 512;
    const size_t gA_w = ((size_t)blockIdx.x * KC + wave) << 10;
    const size_t gB_w = ((size_t)blockIdx.y * KC + wave) << 10;
    const int l8 = lane * 8;

    f32x4 acc[4][4];
#pragma unroll
    for (int i = 0; i < 4; ++i)
#pragma unroll
        for (int j = 0; j < 4; ++j) acc[i][j] = (f32x4){0.f, 0.f, 0.f, 0.f};

    for (int phase = 0; phase < 2; ++phase) {
        const ushort_t* __restrict__ Ah = phase ? Axh : Amh;
        const ushort_t* __restrict__ Bh = phase ? Brh : Blh;
        const ushort_t* __restrict__ Bl = phase ? Brl : Bll;
        for (int k0 = 0; k0 < K; k0 += 32) {
            const size_t ga = gA_w + ((size_t)(k0 >> 3) << 10) + l8;
            const size_t gb = gB_w + ((size_t)(k0 >> 3) << 10) + l8;
            __syncthreads();
            async_ld16(Ah + ga, &As_h[s0]);
            async_ld16(Ah + ga + 512, &As_h[s1]);
            async_ld16(Bh + gb, &Bs_h[s0]);
            async_ld16(Bh + gb + 512, &Bs_h[s1]);
            async_ld16(Bl + gb, &Bs_l[s0]);
            async_ld16(Bl + gb + 512, &Bs_l[s1]);
            __syncthreads();

            short8 fah[4], fbh[4], fbl[4];
#pragma unroll
            for (int i = 0; i < 4; ++i) {
                const int aoff = quad * 1024 + (wm + i * 16 + l15) * 8;
                const int boff = quad * 1024 + (wn + i * 16 + l15) * 8;
                fah[i] = *(const short8*)&As_h[aoff];
                fbh[i] = *(const short8*)&Bs_h[boff];
                fbl[i] = *(const short8*)&Bs_l[boff];
            }
#pragma unroll
            for (int i = 0; i < 4; ++i)
#pragma unroll
                for (int j = 0; j < 4; ++j) {
                    acc[i][j] = __builtin_amdgcn_mfma_f32_16x16x32_bf16(fah[i], fbh[j], acc[i][j], 0, 0, 0);
                    acc[i][j] = __builtin_amdgcn_mfma_f32_16x16x32_bf16(fah[i], fbl[j], acc[i][j], 0, 0, 0);
                }
        }
    }

    const size_t otile = (size_t)blockIdx.x * (N >> 3) * 1024;
#pragma unroll
    for (int i = 0; i < 4; ++i) {
        const int mr0 = wm + i * 16 + quad * 4;
#pragma unroll
        for (int j = 0; j < 4; ++j) {
            const int col = bn + wn + j * 16 + l15;
            const float bv = bias[col];
            const size_t cbase = otile + (size_t)(col >> 3) * 1024 + (col & 7);
#pragma unroll
            for (int r = 0; r < 4; ++r) {
                const int row = bm + mr0 + r;
                if (row < M) {
                    float y = fmaxf(acc[i][j][r] + bv, 0.f);
                    const ushort_t hb = f2bf(y);
                    Oh[cbase + (size_t)(mr0 + r) * 8] = hb;
                    if (Orow) Orow[(size_t)row * N + col] = hb;
                }
            }
        }
    }
}

// ---------------- R10's EXACT GEMM3+FC instantiation ------------------------
__global__ __launch_bounds__(256) void mfma_sage_gemm_fc(
    const ushort_t* __restrict__ Amh,
    const ushort_t* __restrict__ Axh, const ushort_t* __restrict__ Axl,
    const ushort_t* __restrict__ Blh, const ushort_t* __restrict__ Bll,
    const ushort_t* __restrict__ Brh, const ushort_t* __restrict__ Brl,
    const float* __restrict__ bias, ushort_t* __restrict__ Oh,
    ushort_t* __restrict__ Orow,
    const float* __restrict__ Wfc, float* __restrict__ part,
    int M, int K, int N, int axl_valid)
{
    __shared__ ushort_t smem[128 * YT_STRIDE];
    __shared__ float wlds[1152];
    ushort_t* As_h = smem;
    ushort_t* As_l = smem + 4096;
    ushort_t* Bs_h = smem + 8192;
    ushort_t* Bs_l = smem + 12288;

    const int tid  = threadIdx.x;
    const int lane = tid & 63;
    const int wave = tid >> 6;
    const int wm = (wave & 1) * 64;
    const int wn = (wave >> 1) * 64;
    const int l15 = lane & 15;
    const int quad = lane >> 4;
    const int bm = blockIdx.x * 128;
    const int bn = blockIdx.y * 128;
    const int KC = K >> 3;

    const int s0 = wave * 1024 + lane * 8;
    const int s1 = s0 + 512;
    const size_t gA_w = ((size_t)blockIdx.x * KC + wave) << 10;
    const size_t gB_w = ((size_t)blockIdx.y * KC + wave) << 10;
    const int l8 = lane * 8;

    f32x4 acc[4][4];
#pragma unroll
    for (int i = 0; i < 4; ++i)
#pragma unroll
        for (int j = 0; j < 4; ++j) acc[i][j] = (f32x4){0.f, 0.f, 0.f, 0.f};

    for (int phase = 0; phase < 2; ++phase) {
        const ushort_t* __restrict__ Ah = phase ? Axh : Amh;
        const ushort_t* __restrict__ Al = phase ? Axl : (const ushort_t*)nullptr;
        const ushort_t* __restrict__ Bh = phase ? Brh : Blh;
        const ushort_t* __restrict__ Bl = phase ? Brl : Bll;
        const bool doAl = (phase == 1) && (axl_valid != 0);
        for (int k0 = 0; k0 < K; k0 += 32) {
            const size_t ga = gA_w + ((size_t)(k0 >> 3) << 10) + l8;
            const size_t gb = gB_w + ((size_t)(k0 >> 3) << 10) + l8;
            __syncthreads();   // protect LDS reuse
            async_ld16(Ah + ga, &As_h[s0]);
            async_ld16(Ah + ga + 512, &As_h[s1]);
            if (doAl) {
                async_ld16(Al + ga, &As_l[s0]);
                async_ld16(Al + ga + 512, &As_l[s1]);
            }
            async_ld16(Bh + gb, &Bs_h[s0]);
            async_ld16(Bh + gb + 512, &Bs_h[s1]);
            async_ld16(Bl + gb, &Bs_l[s0]);
            async_ld16(Bl + gb + 512, &Bs_l[s1]);
            __syncthreads();   // drains vmcnt (global_load_lds)

            short8 fah[4], fal[4], fbh[4], fbl[4];
#pragma unroll
            for (int i = 0; i < 4; ++i) {
                const int aoff = quad * 1024 + (wm + i * 16 + l15) * 8;
                const int boff = quad * 1024 + (wn + i * 16 + l15) * 8;
                fah[i] = *(const short8*)&As_h[aoff];
                fbh[i] = *(const short8*)&Bs_h[boff];
                fbl[i] = *(const short8*)&Bs_l[boff];
                if (doAl) fal[i] = *(const short8*)&As_l[aoff];
            }
#pragma unroll
            for (int i = 0; i < 4; ++i)
#pragma unroll
                for (int j = 0; j < 4; ++j) {
                    acc[i][j] = __builtin_amdgcn_mfma_f32_16x16x32_bf16(fah[i], fbh[j], acc[i][j], 0, 0, 0);
                    acc[i][j] = __builtin_amdgcn_mfma_f32_16x16x32_bf16(fah[i], fbl[j], acc[i][j], 0, 0, 0);
                    if (doAl)
                        acc[i][j] = __builtin_amdgcn_mfma_f32_16x16x32_bf16(fal[i], fbh[j], acc[i][j], 0, 0, 0);
                }
        }
    }

    // fused FC epilogue (R10 scalar-LDS form)
    __syncthreads();
    for (int i = tid; i < 1152; i += 256)
        wlds[i] = Wfc[(size_t)blockIdx.y * 1152 + i];
#pragma unroll
    for (int i = 0; i < 4; ++i) {
        const int mr0 = wm + i * 16 + quad * 4;
#pragma unroll
        for (int j = 0; j < 4; ++j) {
            const int colL = wn + j * 16 + l15;       // 0..127 local
            const float bv = bias[bn + colL];
#pragma unroll
            for (int r = 0; r < 4; ++r) {
                float y = fmaxf(acc[i][j][r] + bv, 0.f);
                smem[(mr0 + r) * YT_STRIDE + colL] = f2bf(y);
            }
        }
    }
    __syncthreads();
    const int rowL = tid >> 1;
    const int kh = (tid & 1) * 64;
    float s[9];
#pragma unroll
    for (int fc = 0; fc < 9; ++fc) s[fc] = 0.f;
    for (int k = 0; k < 64; ++k) {
        const float y = bf2f(smem[rowL * YT_STRIDE + kh + k]);
        const float* wr = &wlds[(kh + k) * 9];
#pragma unroll
        for (int fc = 0; fc < 9; ++fc) s[fc] += y * wr[fc];
    }
#pragma unroll
    for (int fc = 0; fc < 9; ++fc) s[fc] += __shfl_down(s[fc], 1);
    const int grow = bm + rowL;
    if (((tid & 1) == 0) && grow < M) {
        float* po = part + (size_t)blockIdx.y * (size_t)M * 9 + (size_t)grow * 9;
#pragma unroll
        for (int fc = 0; fc < 9; ++fc) po[fc] = s[fc];
    }
    (void)Oh; (void)Orow;
}

// ---------------- fc_sum: out = part0 + part1 + bias ----------------
__global__ __launch_bounds__(256) void fc_sum_kernel(
    const float* __restrict__ part, const float* __restrict__ b,
    float* __restrict__ outp, int M)
{
    __shared__ float bs[N_OUT];
    if (threadIdx.x < N_OUT) bs[threadIdx.x] = b[threadIdx.x];
    __syncthreads();
    const int t = blockIdx.x * 256 + threadIdx.x;
    const int total = M * N_OUT;
    if (t >= total) return;
    const int fc = t % N_OUT;
    outp[t] = part[t] + part[(size_t)M * 9 + t] + bs[fc];
}

extern "C" void kernel_launch(void* const* d_in, const int* in_sizes, int n_in,
                              void* d_out, int out_size, void* d_ws, size_t ws_size,
                              hipStream_t stream) {
    const float* x   = (const float*)d_in[0];
    const int*   ei  = (const int*)d_in[1];
    const float* Wl1 = (const float*)d_in[2];
    const float* bl1 = (const float*)d_in[3];
    const float* Wr1 = (const float*)d_in[4];
    const float* Wl2 = (const float*)d_in[5];
    const float* bl2 = (const float*)d_in[6];
    const float* Wr2 = (const float*)d_in[7];
    const float* Wl3 = (const float*)d_in[8];
    const float* bl3 = (const float*)d_in[9];
    const float* Wr3 = (const float*)d_in[10];
    const float* Wfc = (const float*)d_in[11];
    const float* bfc = (const float*)d_in[12];
    float* outp = (float*)d_out;

    const int M = in_sizes[0] / N_IN;        // 100000
    const int E = in_sizes[1] / 2;           // 1600000
    const int* src = ei;
    const int* dst = ei + E;
    const size_t Mrow = 100352;              // 784 tiles of 128 rows
    const int nbuck = (M + 127) / 128;       // 782 (< NBUCK_MAX)
    const int chunk = (E + EB - 1) / EB;     // 3125

    // -------- workspace carve --------
    char* base = (char*)d_ws;
    char* p = base;
    int*   degi      = (int*)p;   p += Mrow * 4;
    int*   row_start = (int*)p;   p += Mrow * 4;
    float* invdeg    = (float*)p; p += Mrow * 4;
    uint_t* cnt      = (uint_t*)p; p += (size_t)EB * NBUCK_MAX * 4;   // 1.6 MB
    uint_t* totalv   = (uint_t*)p; p += NBUCK_MAX * 4;
    uint_t* basev    = (uint_t*)p; p += NBUCK_MAX * 4;
    uint_t* ebuf     = (uint_t*)p; p += ((size_t)E + 3) / 4 * 16;     // 6.4 MB
    int*   colA      = (int*)p;   p += ((size_t)E + 3) / 4 * 16;      // 6.4 MB
    ushort_t* xh     = (ushort_t*)p; p += Mrow * 64 * 2;   // tiled hi
    ushort_t* xrow   = (ushort_t*)p; p += Mrow * 64 * 2;   // row-major (gather1)
    ushort_t* h1h    = (ushort_t*)p; p += Mrow * 128 * 2;  // tiled
    ushort_t* h1row  = (ushort_t*)p; p += Mrow * 128 * 2;  // row-major (gather2)
    ushort_t* aggh   = (ushort_t*)p; p += Mrow * 128 * 2;  // tiled hi-only
    ushort_t* h2h    = (ushort_t*)p; p += Mrow * 128 * 2;  // tiled
    ushort_t* h2row  = (ushort_t*)p; p += Mrow * 128 * 2;  // row-major (gather3)
    float* part      = (float*)p; p += (size_t)2 * M * 9 * 4;         // 7.2 MB
    ushort_t* w1lh = (ushort_t*)p; p += 64 * 128 * 2;
    ushort_t* w1ll = (ushort_t*)p; p += 64 * 128 * 2;
    ushort_t* w1rh = (ushort_t*)p; p += 64 * 128 * 2;
    ushort_t* w1rl = (ushort_t*)p; p += 64 * 128 * 2;
    ushort_t* w2lh = (ushort_t*)p; p += 128 * 128 * 2;
    ushort_t* w2ll = (ushort_t*)p; p += 128 * 128 * 2;
    ushort_t* w2rh = (ushort_t*)p; p += 128 * 128 * 2;
    ushort_t* w2rl = (ushort_t*)p; p += 128 * 128 * 2;
    ushort_t* w3lh = (ushort_t*)p; p += 128 * 256 * 2;
    ushort_t* w3ll = (ushort_t*)p; p += 128 * 256 * 2;
    ushort_t* w3rh = (ushort_t*)p; p += 128 * 256 * 2;
    ushort_t* w3rl = (ushort_t*)p; p += 128 * 256 * 2;
    (void)ws_size; (void)n_in; (void)out_size;

    const int blk = 256;
    const int grid_m = (M + 127) / 128;      // 782

    // -------- fused csr_count + prep_split --------
    {
        const int prep_total = M * 8 + 114688;
        const int prep_blocks = (prep_total + blk - 1) / blk;
        csr_count_prep<<<EB + prep_blocks, blk, 0, stream>>>(
            dst, cnt, E, nbuck, chunk,
            x, xh, xrow, M, Wl1, Wr1, Wl2, Wr2, Wl3, Wr3,
            w1lh, w1ll, w1rh, w1rl, w2lh, w2ll, w2rh, w2rl, w3lh, w3ll, w3rh, w3rl);
    }

    // -------- CSR build (bucketed shuffle, no global atomics) --------
    csr_colscan<<<nbuck, 512, 0, stream>>>(cnt, totalv, nbuck);
    top_scan_1024<<<1, 1024, 0, stream>>>(totalv, basev, nbuck);
    csr_scatter<<<EB, blk, 0, stream>>>(src, dst, cnt, basev, ebuf, E, nbuck, chunk);
    csr_final<<<nbuck, blk, 0, stream>>>(ebuf, basev, totalv, colA, row_start, degi, invdeg, M);

    // -------- layer 1: 64 -> 128 (gather reads xrow; self term xh hi) --------
    gather_mean_hi<8><<<(M + 7) / 8, blk, 0, stream>>>(
        xrow, colA, row_start, degi, invdeg, aggh, M);
    mfma_sage_gemm2<<<dim3(grid_m, 1), blk, 0, stream>>>(
        aggh, xh, w1lh, w1ll, w1rh, w1rl, bl1, h1h, h1row, M, 64, 128);

    // -------- layer 2: 128 -> 128 (gather reads h1row; self h1 tiled hi) ------
    gather_mean_hi<16><<<(M + 3) / 4, blk, 0, stream>>>(
        h1row, colA, row_start, degi, invdeg, aggh, M);
    mfma_sage_gemm2<<<dim3(grid_m, 1), blk, 0, stream>>>(
        aggh, h1h, w2lh, w2ll, w2rh, w2rl, bl2, h2h, h2row, M, 128, 128);

    // -------- layer 3: 128 -> 256 with fused FC (R10's exact kernel) --------
    gather_mean_hi<16><<<(M + 3) / 4, blk, 0, stream>>>(
        h2row, colA, row_start, degi, invdeg, aggh, M);
    mfma_sage_gemm_fc<<<dim3(grid_m, 2), blk, 0, stream>>>(
        aggh, h2h, (const ushort_t*)nullptr, w3lh, w3ll, w3rh, w3rl, bl3,
        (ushort_t*)nullptr, (ushort_t*)nullptr, Wfc, part, M, 128, 256, 0);

    // -------- fc_sum: out = part0 + part1 + bias --------
    fc_sum_kernel<<<(M * N_OUT + blk - 1) / blk, blk, 0, stream>>>(part, bfc, outp, M);
}

// Round 17
// 433.809 us; speedup vs baseline: 1.0384x; 1.0384x over previous
//
#include <hip/hip_runtime.h>
#include <cstddef>
#include <cstdint>

// GraphSAGE (3x SAGEConv mean-aggr + FC) on MI355X.
// Round 16 = exact revert to R14 (best measured: 439.1us).
// R15's 4-way gather split regressed (avg degree 16 -> quarters of ~4
// neighbors defeat the unroll-4 body; 2-way halves of ~8 are optimal) and
// the count+prep fusion showed no win. Restoring the measured-best config:
//  - 2-way neighbor-split gathers
//  - separate csr_count and prep_split launches
//  - GEMM1/2: 2-term kernel (x-lo dropped, 24KB LDS)
//  - GEMM3+FC: R10's exact instantiation (VGPR 80, scalar-LDS FC epilogue)
//  - bucketed-shuffle CSR, dual layout, hi-only activations, split-bf16 W.

typedef unsigned int uint_t;
typedef unsigned short ushort_t;
typedef __attribute__((ext_vector_type(8))) short short8;
typedef __attribute__((ext_vector_type(4))) float f32x4;

#define N_IN 64
#define N_HID 128
#define N_OUT 9
#define EB 512          // edge blocks for P1/P3
#define NBUCK_MAX 800   // >= ceil(M/128)
#define YT_STRIDE 134   // y-tile LDS stride (ushorts) for FC epilogue

__device__ __forceinline__ ushort_t f2bf(float f) {   // fp32 -> bf16 RNE
    uint_t u = __float_as_uint(f);
    u += 0x7fffu + ((u >> 16) & 1u);
    return (ushort_t)(u >> 16);
}
__device__ __forceinline__ float bf2f(ushort_t h) {
    return __uint_as_float(((uint_t)h) << 16);
}
__device__ __forceinline__ void async_ld16(const void* g, void* l) {
    __builtin_amdgcn_global_load_lds((const __attribute__((address_space(1))) void*)g,
                                     (__attribute__((address_space(3))) void*)l, 16, 0, 0);
}

// ---------------- CSR build: bucketed shuffle (no global atomics) ----------
__global__ __launch_bounds__(256) void csr_count(const int* __restrict__ dst,
                                                 uint_t* __restrict__ cnt,
                                                 int E, int nbuck, int chunk) {
    __shared__ uint_t c[NBUCK_MAX];
    for (int i = threadIdx.x; i < nbuck; i += 256) c[i] = 0;
    __syncthreads();
    const int beg = blockIdx.x * chunk;
    const int end = min(beg + chunk, E);
    for (int i = beg + threadIdx.x; i < end; i += 256)
        atomicAdd(&c[dst[i] >> 7], 1u);           // LDS atomic
    __syncthreads();
    for (int i = threadIdx.x; i < nbuck; i += 256)
        cnt[(size_t)blockIdx.x * nbuck + i] = c[i];
}

__global__ __launch_bounds__(512) void csr_colscan(uint_t* __restrict__ cnt,
                                                   uint_t* __restrict__ total, int nbuck) {
    __shared__ uint_t sm[512];
    const int b = blockIdx.x;
    const uint_t v = cnt[(size_t)threadIdx.x * nbuck + b];
    sm[threadIdx.x] = v;
    __syncthreads();
    for (int off = 1; off < 512; off <<= 1) {
        uint_t t = (threadIdx.x >= off) ? sm[threadIdx.x - off] : 0;
        __syncthreads();
        sm[threadIdx.x] += t;
        __syncthreads();
    }
    cnt[(size_t)threadIdx.x * nbuck + b] = sm[threadIdx.x] - v;   // exclusive
    if (threadIdx.x == 511) total[b] = sm[511];
}

__global__ __launch_bounds__(1024) void top_scan_1024(const uint_t* __restrict__ total,
                                                      uint_t* __restrict__ basev, int nb) {
    __shared__ uint_t sm[1024];
    const int i = threadIdx.x;
    const uint_t v = (i < nb) ? total[i] : 0;
    sm[i] = v;
    __syncthreads();
    for (int off = 1; off < 1024; off <<= 1) {
        uint_t t = (i >= off) ? sm[i - off] : 0;
        __syncthreads();
        sm[i] += t;
        __syncthreads();
    }
    if (i < nb) basev[i] = sm[i] - v;   // exclusive
}

__global__ __launch_bounds__(256) void csr_scatter(const int* __restrict__ src,
                                                   const int* __restrict__ dst,
                                                   const uint_t* __restrict__ cnt,
                                                   const uint_t* __restrict__ basev,
                                                   uint_t* __restrict__ ebuf,
                                                   int E, int nbuck, int chunk) {
    __shared__ uint_t cur[NBUCK_MAX];
    for (int i = threadIdx.x; i < nbuck; i += 256)
        cur[i] = basev[i] + cnt[(size_t)blockIdx.x * nbuck + i];
    __syncthreads();
    const int beg = blockIdx.x * chunk;
    const int end = min(beg + chunk, E);
    for (int i = beg + threadIdx.x; i < end; i += 256) {
        const int d = dst[i];
        const uint_t pos = atomicAdd(&cur[d >> 7], 1u);   // LDS atomic
        ebuf[pos] = ((uint_t)src[i] << 7) | (uint_t)(d & 127);
    }
}

__global__ __launch_bounds__(256) void csr_final(const uint_t* __restrict__ ebuf,
                                                 const uint_t* __restrict__ basev,
                                                 const uint_t* __restrict__ total,
                                                 int* __restrict__ colA,
                                                 int* __restrict__ row_start,
                                                 int* __restrict__ degi,
                                                 float* __restrict__ invdeg, int M) {
    __shared__ uint_t c128[128];
    __shared__ uint_t cur[128];
    __shared__ uint_t sm[256];
    const int b = blockIdx.x;
    const int nbase = b << 7;
    const uint_t e0 = basev[b];
    const uint_t T = total[b];
    if (threadIdx.x < 128) c128[threadIdx.x] = 0;
    __syncthreads();
    for (uint_t i = threadIdx.x; i < T; i += 256)
        atomicAdd(&c128[ebuf[e0 + i] & 127], 1u);
    __syncthreads();
    const uint_t v = (threadIdx.x < 128) ? c128[threadIdx.x] : 0;
    sm[threadIdx.x] = v;
    __syncthreads();
    for (int off = 1; off < 128; off <<= 1) {
        uint_t t = (threadIdx.x >= off) ? sm[threadIdx.x - off] : 0;
        __syncthreads();
        sm[threadIdx.x] += t;
        __syncthreads();
    }
    if (threadIdx.x < 128) {
        const uint_t ex = sm[threadIdx.x] - v;   // exclusive within bucket
        cur[threadIdx.x] = ex;
        const int node = nbase + threadIdx.x;
        if (node < M) {
            degi[node] = (int)v;
            invdeg[node] = 1.0f / fmaxf((float)v, 1.0f);
            row_start[node] = (int)(e0 + ex);
        }
    }
    __syncthreads();
    for (uint_t i = threadIdx.x; i < T; i += 256) {
        const uint_t p = ebuf[e0 + i];
        const uint_t pos = atomicAdd(&cur[p & 127], 1u);
        colA[e0 + pos] = (int)(p >> 7);
    }
}

// ---------------- prep: x split (tiled hi + row copy) AND all 6 W splits ----
__global__ __launch_bounds__(256) void prep_split(
    const float* __restrict__ X, ushort_t* __restrict__ xh,
    ushort_t* __restrict__ xrow, int M,
    const float* __restrict__ Wl1, const float* __restrict__ Wr1,
    const float* __restrict__ Wl2, const float* __restrict__ Wr2,
    const float* __restrict__ Wl3, const float* __restrict__ Wr3,
    ushort_t* __restrict__ w1lh, ushort_t* __restrict__ w1ll,
    ushort_t* __restrict__ w1rh, ushort_t* __restrict__ w1rl,
    ushort_t* __restrict__ w2lh, ushort_t* __restrict__ w2ll,
    ushort_t* __restrict__ w2rh, ushort_t* __restrict__ w2rl,
    ushort_t* __restrict__ w3lh, ushort_t* __restrict__ w3ll,
    ushort_t* __restrict__ w3rh, ushort_t* __restrict__ w3rl)
{
    int idx = blockIdx.x * 256 + threadIdx.x;
    const int xn = M * 8;
    if (idx < xn) {
        const int node = idx >> 3;
        const int ch = idx & 7;
        const float4 f0 = *(const float4*)(X + (size_t)node * 64 + ch * 8);
        const float4 f1 = *(const float4*)(X + (size_t)node * 64 + ch * 8 + 4);
        float e[8] = {f0.x, f0.y, f0.z, f0.w, f1.x, f1.y, f1.z, f1.w};
        uint_t hv[4];
#pragma unroll
        for (int t = 0; t < 4; ++t) {
            ushort_t h0 = f2bf(e[2 * t]), h1 = f2bf(e[2 * t + 1]);
            hv[t] = (uint_t)h0 | ((uint_t)h1 << 16);
        }
        const size_t off = ((size_t)(node >> 7) * 8 + ch) * 1024 + (node & 127) * 8;
        const uint4 hq = make_uint4(hv[0], hv[1], hv[2], hv[3]);
        *(uint4*)(xh + off) = hq;
        *(uint4*)(xrow + (size_t)node * 64 + ch * 8) = hq;
        return;
    }
    idx -= xn;
    const float* W; ushort_t* th; ushort_t* tl; int K, N, e;
    if (idx < 8192)        { W = Wl1; th = w1lh; tl = w1ll; K = 64;  N = 128; e = idx; }
    else if (idx < 16384)  { W = Wr1; th = w1rh; tl = w1rl; K = 64;  N = 128; e = idx - 8192; }
    else if (idx < 32768)  { W = Wl2; th = w2lh; tl = w2ll; K = 128; N = 128; e = idx - 16384; }
    else if (idx < 49152)  { W = Wr2; th = w2rh; tl = w2rl; K = 128; N = 128; e = idx - 32768; }
    else if (idx < 81920)  { W = Wl3; th = w3lh; tl = w3ll; K = 128; N = 256; e = idx - 49152; }
    else if (idx < 114688) { W = Wr3; th = w3rh; tl = w3rl; K = 128; N = 256; e = idx - 81920; }
    else return;
    int k = e / N, n = e - k * N;
    float v = W[e];
    ushort_t hb = f2bf(v);
    const size_t off = ((size_t)(n >> 7) * (K >> 3) + (k >> 3)) * 1024 + (n & 127) * 8 + (k & 7);
    th[off] = hb;
    tl[off] = f2bf(v - bf2f(hb));
}

// ---------------- gather-mean (ROW-MAJOR hi input, tiled HI output) ----------
// Neighbor-split: 2*CH threads/node; halves combined with one __shfl_xor(a,CH).
__device__ __forceinline__ void acc8_hi(float* a, uint4 h) {
    a[0] += __uint_as_float(h.x << 16);
    a[1] += __uint_as_float(h.x & 0xffff0000u);
    a[2] += __uint_as_float(h.y << 16);
    a[3] += __uint_as_float(h.y & 0xffff0000u);
    a[4] += __uint_as_float(h.z << 16);
    a[5] += __uint_as_float(h.z & 0xffff0000u);
    a[6] += __uint_as_float(h.w << 16);
    a[7] += __uint_as_float(h.w & 0xffff0000u);
}

template <int CH>
__global__ __launch_bounds__(256) void gather_mean_hi(
    const ushort_t* __restrict__ fh, const int* __restrict__ colA,
    const int* __restrict__ row_start, const int* __restrict__ degi,
    const float* __restrict__ invdeg,
    ushort_t* __restrict__ oh, int M)
{
    constexpr int TPN = 2 * CH;           // threads per node
    constexpr int SLOTS = 256 / TPN;
    constexpr int DIM = CH * 8;
    const int tid = threadIdx.x;
    const int ch = tid & (CH - 1);
    const int half = (tid & CH) ? 1 : 0;
    const int slot = tid / TPN;
    const int node = blockIdx.x * SLOTS + slot;
    if (node >= M) return;
    const int beg = row_start[node];
    const int cnt = degi[node];
    const int hmid = cnt >> 1;
    const int jb = half ? hmid : 0;
    const int je = half ? cnt : hmid;
    float a[8];
#pragma unroll
    for (int t = 0; t < 8; ++t) a[t] = 0.f;
    int j = jb;
    for (; j + 3 < je; j += 4) {
        const int s0 = colA[beg + j];
        const int s1 = colA[beg + j + 1];
        const int s2 = colA[beg + j + 2];
        const int s3 = colA[beg + j + 3];
        const uint4 h0 = *(const uint4*)(fh + (size_t)s0 * DIM + ch * 8);
        const uint4 h1 = *(const uint4*)(fh + (size_t)s1 * DIM + ch * 8);
        const uint4 h2 = *(const uint4*)(fh + (size_t)s2 * DIM + ch * 8);
        const uint4 h3 = *(const uint4*)(fh + (size_t)s3 * DIM + ch * 8);
        acc8_hi(a, h0);
        acc8_hi(a, h1);
        acc8_hi(a, h2);
        acc8_hi(a, h3);
    }
    for (; j < je; ++j) {
        const int s0 = colA[beg + j];
        const uint4 h0 = *(const uint4*)(fh + (size_t)s0 * DIM + ch * 8);
        acc8_hi(a, h0);
    }
    // combine halves (partner lane = lane ^ CH, same wave)
#pragma unroll
    for (int t = 0; t < 8; ++t) a[t] += __shfl_xor(a[t], CH);
    if (half) return;
    const float sc = invdeg[node];
    uint_t hv[4];
#pragma unroll
    for (int t = 0; t < 4; ++t) {
        ushort_t hb0 = f2bf(a[2 * t] * sc), hb1 = f2bf(a[2 * t + 1] * sc);
        hv[t] = (uint_t)hb0 | ((uint_t)hb1 << 16);
    }
    const size_t off = ((size_t)(node >> 7) * CH + ch) * 1024 + (node & 127) * 8;
    *(uint4*)(oh + off) = make_uint4(hv[0], hv[1], hv[2], hv[3]);
}

// ---------------- 2-term GEMM (layers 1-2): 24KB LDS ------------------------
// y = relu( mean @ Wl + x @ Wr + bias ); stores tiled hi + row-major hi.
__global__ __launch_bounds__(256) void mfma_sage_gemm2(
    const ushort_t* __restrict__ Amh, const ushort_t* __restrict__ Axh,
    const ushort_t* __restrict__ Blh, const ushort_t* __restrict__ Bll,
    const ushort_t* __restrict__ Brh, const ushort_t* __restrict__ Brl,
    const float* __restrict__ bias, ushort_t* __restrict__ Oh,
    ushort_t* __restrict__ Orow,
    int M, int K, int N)
{
    __shared__ ushort_t As_h[4096];
    __shared__ ushort_t Bs_h[4096];
    __shared__ ushort_t Bs_l[4096];

    const int tid  = threadIdx.x;
    const int lane = tid & 63;
    const int wave = tid >> 6;
    const int wm = (wave & 1) * 64;
    const int wn = (wave >> 1) * 64;
    const int l15 = lane & 15;
    const int quad = lane >> 4;
    const int bm = blockIdx.x * 128;
    const int bn = blockIdx.y * 128;
    const int KC = K >> 3;

    const int s0 = wave * 1024 + lane * 8;
    const int s1 = s0 + 512;
    const size_t gA_w = ((size_t)blockIdx.x * KC + wave) << 10;
    const size_t gB_w = ((size_t)blockIdx.y * KC + wave) << 10;
    const int l8 = lane * 8;

    f32x4 acc[4][4];
#pragma unroll
    for (int i = 0; i < 4; ++i)
#pragma unroll
        for (int j = 0; j < 4; ++j) acc[i][j] = (f32x4){0.f, 0.f, 0.f, 0.f};

    for (int phase = 0; phase < 2; ++phase) {
        const ushort_t* __restrict__ Ah = phase ? Axh : Amh;
        const ushort_t* __restrict__ Bh = phase ? Brh : Blh;
        const ushort_t* __restrict__ Bl = phase ? Brl : Bll;
        for (int k0 = 0; k0 < K; k0 += 32) {
            const size_t ga = gA_w + ((size_t)(k0 >> 3) << 10) + l8;
            const size_t gb = gB_w + ((size_t)(k0 >> 3) << 10) + l8;
            __syncthreads();
            async_ld16(Ah + ga, &As_h[s0]);
            async_ld16(Ah + ga + 512, &As_h[s1]);
            async_ld16(Bh + gb, &Bs_h[s0]);
            async_ld16(Bh + gb + 512, &Bs_h[s1]);
            async_ld16(Bl + gb, &Bs_l[s0]);
            async_ld16(Bl + gb + 512, &Bs_l[s1]);
            __syncthreads();

            short8 fah[4], fbh[4], fbl[4];
#pragma unroll
            for (int i = 0; i < 4; ++i) {
                const int aoff = quad * 1024 + (wm + i * 16 + l15) * 8;
                const int boff = quad * 1024 + (wn + i * 16 + l15) * 8;
                fah[i] = *(const short8*)&As_h[aoff];
                fbh[i] = *(const short8*)&Bs_h[boff];
                fbl[i] = *(const short8*)&Bs_l[boff];
            }
#pragma unroll
            for (int i = 0; i < 4; ++i)
#pragma unroll
                for (int j = 0; j < 4; ++j) {
                    acc[i][j] = __builtin_amdgcn_mfma_f32_16x16x32_bf16(fah[i], fbh[j], acc[i][j], 0, 0, 0);
                    acc[i][j] = __builtin_amdgcn_mfma_f32_16x16x32_bf16(fah[i], fbl[j], acc[i][j], 0, 0, 0);
                }
        }
    }

    const size_t otile = (size_t)blockIdx.x * (N >> 3) * 1024;
#pragma unroll
    for (int i = 0; i < 4; ++i) {
        const int mr0 = wm + i * 16 + quad * 4;
#pragma unroll
        for (int j = 0; j < 4; ++j) {
            const int col = bn + wn + j * 16 + l15;
            const float bv = bias[col];
            const size_t cbase = otile + (size_t)(col >> 3) * 1024 + (col & 7);
#pragma unroll
            for (int r = 0; r < 4; ++r) {
                const int row = bm + mr0 + r;
                if (row < M) {
                    float y = fmaxf(acc[i][j][r] + bv, 0.f);
                    const ushort_t hb = f2bf(y);
                    Oh[cbase + (size_t)(mr0 + r) * 8] = hb;
                    if (Orow) Orow[(size_t)row * N + col] = hb;
                }
            }
        }
    }
}

// ---------------- R10's EXACT GEMM3+FC instantiation ------------------------
// (runtime axl_valid, 4-plane smem carve, scalar-LDS FC epilogue; VGPR 80)
__global__ __launch_bounds__(256) void mfma_sage_gemm_fc(
    const ushort_t* __restrict__ Amh,
    const ushort_t* __restrict__ Axh, const ushort_t* __restrict__ Axl,
    const ushort_t* __restrict__ Blh, const ushort_t* __restrict__ Bll,
    const ushort_t* __restrict__ Brh, const ushort_t* __restrict__ Brl,
    const float* __restrict__ bias, ushort_t* __restrict__ Oh,
    ushort_t* __restrict__ Orow,
    const float* __restrict__ Wfc, float* __restrict__ part,
    int M, int K, int N, int axl_valid)
{
    __shared__ ushort_t smem[128 * YT_STRIDE];
    __shared__ float wlds[1152];
    ushort_t* As_h = smem;
    ushort_t* As_l = smem + 4096;
    ushort_t* Bs_h = smem + 8192;
    ushort_t* Bs_l = smem + 12288;

    const int tid  = threadIdx.x;
    const int lane = tid & 63;
    const int wave = tid >> 6;
    const int wm = (wave & 1) * 64;
    const int wn = (wave >> 1) * 64;
    const int l15 = lane & 15;
    const int quad = lane >> 4;
    const int bm = blockIdx.x * 128;
    const int bn = blockIdx.y * 128;
    const int KC = K >> 3;

    const int s0 = wave * 1024 + lane * 8;
    const int s1 = s0 + 512;
    const size_t gA_w = ((size_t)blockIdx.x * KC + wave) << 10;
    const size_t gB_w = ((size_t)blockIdx.y * KC + wave) << 10;
    const int l8 = lane * 8;

    f32x4 acc[4][4];
#pragma unroll
    for (int i = 0; i < 4; ++i)
#pragma unroll
        for (int j = 0; j < 4; ++j) acc[i][j] = (f32x4){0.f, 0.f, 0.f, 0.f};

    for (int phase = 0; phase < 2; ++phase) {
        const ushort_t* __restrict__ Ah = phase ? Axh : Amh;
        const ushort_t* __restrict__ Al = phase ? Axl : (const ushort_t*)nullptr;
        const ushort_t* __restrict__ Bh = phase ? Brh : Blh;
        const ushort_t* __restrict__ Bl = phase ? Brl : Bll;
        const bool doAl = (phase == 1) && (axl_valid != 0);
        for (int k0 = 0; k0 < K; k0 += 32) {
            const size_t ga = gA_w + ((size_t)(k0 >> 3) << 10) + l8;
            const size_t gb = gB_w + ((size_t)(k0 >> 3) << 10) + l8;
            __syncthreads();   // protect LDS reuse
            async_ld16(Ah + ga, &As_h[s0]);
            async_ld16(Ah + ga + 512, &As_h[s1]);
            if (doAl) {
                async_ld16(Al + ga, &As_l[s0]);
                async_ld16(Al + ga + 512, &As_l[s1]);
            }
            async_ld16(Bh + gb, &Bs_h[s0]);
            async_ld16(Bh + gb + 512, &Bs_h[s1]);
            async_ld16(Bl + gb, &Bs_l[s0]);
            async_ld16(Bl + gb + 512, &Bs_l[s1]);
            __syncthreads();   // drains vmcnt (global_load_lds)

            short8 fah[4], fal[4], fbh[4], fbl[4];
#pragma unroll
            for (int i = 0; i < 4; ++i) {
                const int aoff = quad * 1024 + (wm + i * 16 + l15) * 8;
                const int boff = quad * 1024 + (wn + i * 16 + l15) * 8;
                fah[i] = *(const short8*)&As_h[aoff];
                fbh[i] = *(const short8*)&Bs_h[boff];
                fbl[i] = *(const short8*)&Bs_l[boff];
                if (doAl) fal[i] = *(const short8*)&As_l[aoff];
            }
#pragma unroll
            for (int i = 0; i < 4; ++i)
#pragma unroll
                for (int j = 0; j < 4; ++j) {
                    acc[i][j] = __builtin_amdgcn_mfma_f32_16x16x32_bf16(fah[i], fbh[j], acc[i][j], 0, 0, 0);
                    acc[i][j] = __builtin_amdgcn_mfma_f32_16x16x32_bf16(fah[i], fbl[j], acc[i][j], 0, 0, 0);
                    if (doAl)
                        acc[i][j] = __builtin_amdgcn_mfma_f32_16x16x32_bf16(fal[i], fbh[j], acc[i][j], 0, 0, 0);
                }
        }
    }

    // fused FC epilogue (R10 scalar-LDS form)
    __syncthreads();   // last k-iter LDS reads done before reuse as ytile
    for (int i = tid; i < 1152; i += 256)
        wlds[i] = Wfc[(size_t)blockIdx.y * 1152 + i];
    // y-tile -> LDS bf16, stride YT_STRIDE
#pragma unroll
    for (int i = 0; i < 4; ++i) {
        const int mr0 = wm + i * 16 + quad * 4;
#pragma unroll
        for (int j = 0; j < 4; ++j) {
            const int colL = wn + j * 16 + l15;       // 0..127 local
            const float bv = bias[bn + colL];
#pragma unroll
            for (int r = 0; r < 4; ++r) {
                float y = fmaxf(acc[i][j][r] + bv, 0.f);
                smem[(mr0 + r) * YT_STRIDE + colL] = f2bf(y);
            }
        }
    }
    __syncthreads();
    // per-row 9-dim dot over this block's 128 cols; thread pair splits k
    const int rowL = tid >> 1;
    const int kh = (tid & 1) * 64;
    float s[9];
#pragma unroll
    for (int fc = 0; fc < 9; ++fc) s[fc] = 0.f;
    for (int k = 0; k < 64; ++k) {
        const float y = bf2f(smem[rowL * YT_STRIDE + kh + k]);
        const float* wr = &wlds[(kh + k) * 9];
#pragma unroll
        for (int fc = 0; fc < 9; ++fc) s[fc] += y * wr[fc];
    }
#pragma unroll
    for (int fc = 0; fc < 9; ++fc) s[fc] += __shfl_down(s[fc], 1);
    const int grow = bm + rowL;
    if (((tid & 1) == 0) && grow < M) {
        float* po = part + (size_t)blockIdx.y * (size_t)M * 9 + (size_t)grow * 9;
#pragma unroll
        for (int fc = 0; fc < 9; ++fc) po[fc] = s[fc];
    }
    (void)Oh; (void)Orow;
}

// ---------------- fc_sum: out = part0 + part1 + bias ----------------
__global__ __launch_bounds__(256) void fc_sum_kernel(
    const float* __restrict__ part, const float* __restrict__ b,
    float* __restrict__ outp, int M)
{
    __shared__ float bs[N_OUT];
    if (threadIdx.x < N_OUT) bs[threadIdx.x] = b[threadIdx.x];
    __syncthreads();
    const int t = blockIdx.x * 256 + threadIdx.x;
    const int total = M * N_OUT;
    if (t >= total) return;
    const int fc = t % N_OUT;
    outp[t] = part[t] + part[(size_t)M * 9 + t] + bs[fc];
}

extern "C" void kernel_launch(void* const* d_in, const int* in_sizes, int n_in,
                              void* d_out, int out_size, void* d_ws, size_t ws_size,
                              hipStream_t stream) {
    const float* x   = (const float*)d_in[0];
    const int*   ei  = (const int*)d_in[1];
    const float* Wl1 = (const float*)d_in[2];
    const float* bl1 = (const float*)d_in[3];
    const float* Wr1 = (const float*)d_in[4];
    const float* Wl2 = (const float*)d_in[5];
    const float* bl2 = (const float*)d_in[6];
    const float* Wr2 = (const float*)d_in[7];
    const float* Wl3 = (const float*)d_in[8];
    const float* bl3 = (const float*)d_in[9];
    const float* Wr3 = (const float*)d_in[10];
    const float* Wfc = (const float*)d_in[11];
    const float* bfc = (const float*)d_in[12];
    float* outp = (float*)d_out;

    const int M = in_sizes[0] / N_IN;        // 100000
    const int E = in_sizes[1] / 2;           // 1600000
    const int* src = ei;
    const int* dst = ei + E;
    const size_t Mrow = 100352;              // 784 tiles of 128 rows
    const int nbuck = (M + 127) / 128;       // 782 (< NBUCK_MAX)
    const int chunk = (E + EB - 1) / EB;     // 3125

    // -------- workspace carve --------
    char* base = (char*)d_ws;
    char* p = base;
    int*   degi      = (int*)p;   p += Mrow * 4;
    int*   row_start = (int*)p;   p += Mrow * 4;
    float* invdeg    = (float*)p; p += Mrow * 4;
    uint_t* cnt      = (uint_t*)p; p += (size_t)EB * NBUCK_MAX * 4;   // 1.6 MB
    uint_t* totalv   = (uint_t*)p; p += NBUCK_MAX * 4;
    uint_t* basev    = (uint_t*)p; p += NBUCK_MAX * 4;
    uint_t* ebuf     = (uint_t*)p; p += ((size_t)E + 3) / 4 * 16;     // 6.4 MB
    int*   colA      = (int*)p;   p += ((size_t)E + 3) / 4 * 16;      // 6.4 MB
    ushort_t* xh     = (ushort_t*)p; p += Mrow * 64 * 2;   // tiled hi
    ushort_t* xrow   = (ushort_t*)p; p += Mrow * 64 * 2;   // row-major (gather1)
    ushort_t* h1h    = (ushort_t*)p; p += Mrow * 128 * 2;  // tiled
    ushort_t* h1row  = (ushort_t*)p; p += Mrow * 128 * 2;  // row-major (gather2)
    ushort_t* aggh   = (ushort_t*)p; p += Mrow * 128 * 2;  // tiled hi-only
    ushort_t* h2h    = (ushort_t*)p; p += Mrow * 128 * 2;  // tiled
    ushort_t* h2row  = (ushort_t*)p; p += Mrow * 128 * 2;  // row-major (gather3)
    float* part      = (float*)p; p += (size_t)2 * M * 9 * 4;         // 7.2 MB
    ushort_t* w1lh = (ushort_t*)p; p += 64 * 128 * 2;
    ushort_t* w1ll = (ushort_t*)p; p += 64 * 128 * 2;
    ushort_t* w1rh = (ushort_t*)p; p += 64 * 128 * 2;
    ushort_t* w1rl = (ushort_t*)p; p += 64 * 128 * 2;
    ushort_t* w2lh = (ushort_t*)p; p += 128 * 128 * 2;
    ushort_t* w2ll = (ushort_t*)p; p += 128 * 128 * 2;
    ushort_t* w2rh = (ushort_t*)p; p += 128 * 128 * 2;
    ushort_t* w2rl = (ushort_t*)p; p += 128 * 128 * 2;
    ushort_t* w3lh = (ushort_t*)p; p += 128 * 256 * 2;
    ushort_t* w3ll = (ushort_t*)p; p += 128 * 256 * 2;
    ushort_t* w3rh = (ushort_t*)p; p += 128 * 256 * 2;
    ushort_t* w3rl = (ushort_t*)p; p += 128 * 256 * 2;
    (void)ws_size; (void)n_in; (void)out_size;

    const int blk = 256;
    const int grid_m = (M + 127) / 128;      // 782

    // -------- CSR build (bucketed shuffle, no global atomics) --------
    csr_count<<<EB, blk, 0, stream>>>(dst, cnt, E, nbuck, chunk);
    csr_colscan<<<nbuck, 512, 0, stream>>>(cnt, totalv, nbuck);
    top_scan_1024<<<1, 1024, 0, stream>>>(totalv, basev, nbuck);
    csr_scatter<<<EB, blk, 0, stream>>>(src, dst, cnt, basev, ebuf, E, nbuck, chunk);
    csr_final<<<nbuck, blk, 0, stream>>>(ebuf, basev, totalv, colA, row_start, degi, invdeg, M);

    // -------- splits (x + all W, one launch) --------
    {
        const int total = M * 8 + 114688;
        prep_split<<<(total + blk - 1) / blk, blk, 0, stream>>>(
            x, xh, xrow, M, Wl1, Wr1, Wl2, Wr2, Wl3, Wr3,
            w1lh, w1ll, w1rh, w1rl, w2lh, w2ll, w2rh, w2rl, w3lh, w3ll, w3rh, w3rl);
    }

    // -------- layer 1: 64 -> 128 (gather reads xrow; self term xh hi) --------
    gather_mean_hi<8><<<(M + 15) / 16, blk, 0, stream>>>(
        xrow, colA, row_start, degi, invdeg, aggh, M);
    mfma_sage_gemm2<<<dim3(grid_m, 1), blk, 0, stream>>>(
        aggh, xh, w1lh, w1ll, w1rh, w1rl, bl1, h1h, h1row, M, 64, 128);

    // -------- layer 2: 128 -> 128 (gather reads h1row; self h1 tiled hi) ------
    gather_mean_hi<16><<<(M + 7) / 8, blk, 0, stream>>>(
        h1row, colA, row_start, degi, invdeg, aggh, M);
    mfma_sage_gemm2<<<dim3(grid_m, 1), blk, 0, stream>>>(
        aggh, h1h, w2lh, w2ll, w2rh, w2rl, bl2, h2h, h2row, M, 128, 128);

    // -------- layer 3: 128 -> 256 with fused FC (R10's exact kernel) --------
    gather_mean_hi<16><<<(M + 7) / 8, blk, 0, stream>>>(
        h2row, colA, row_start, degi, invdeg, aggh, M);
    mfma_sage_gemm_fc<<<dim3(grid_m, 2), blk, 0, stream>>>(
        aggh, h2h, (const ushort_t*)nullptr, w3lh, w3ll, w3rh, w3rl, bl3,
        (ushort_t*)nullptr, (ushort_t*)nullptr, Wfc, part, M, 128, 256, 0);

    // -------- fc_sum: out = part0 + part1 + bias --------
    fc_sum_kernel<<<(M * N_OUT + blk - 1) / blk, blk, 0, stream>>>(part, bfc, outp, M);
}